// Round 16
// baseline (261.240 us; speedup 1.0000x reference)
//
#include <hip/hip_runtime.h>

// Problem: B=16384, H=2048
//   bdnf = sigmoid(x @ W^T + b)
//   xs   = x * pm
//   fi   = xs * (xs @ M^T) * (0.5/H)
//   out  = xs + bdnf * fi
// Identity: xs @ M^T = x @ (M * pm[col])^T  -> both GEMMs share A = fp8(x).
//
// R16 = R15 + persistent blocks (grid=256, 1 block/CU, 4 row-macro-tiles at
// fixed bcol). Block tails now overlap: xbf epilogue operands prefetched to
// regs after the K-loop's last counted wait; next macro-tile's tile-0 stages
// issued before the epilogue; stores are fire-and-forget, drained by the
// next K-loop's counted waits. FIFO vmcnt ledger per transition:
//   [..<=2 wrap] +32 xpre +8 stages -> VMC(8): xpre done, stages fly
//   +32 stores -> q-top VMC(32): stages done (oldest 8), stores fly
// Fixed bcol => per-block W/M slice (1 MB) is L2-resident across macro-tiles.
// Core K-loop/ledger identical to R8/R15. MX fp8 dual GEMM
// (mfma_scale_f32_16x16x128_f8f6f4, scale_a=127, scale_b=123 undoes x16).

#define M_DIM 16384
#define H_DIM 2048
#define BM 256
#define BN 128
#define BKB 128            // K-tile = 128 fp8 elements = 128 B/row
#define NKT (H_DIM / BKB)  // 16 K-tiles
#define NTHREADS 512
#define NMACRO 4           // row macro-tiles per persistent block

typedef __attribute__((ext_vector_type(4))) int   intx4;
typedef __attribute__((ext_vector_type(8))) int   intx8;
typedef __attribute__((ext_vector_type(4))) float floatx4;

#define GPTR(p) ((const __attribute__((address_space(1))) void*)(p))
#define LPTR(p) ((__attribute__((address_space(3))) void*)(p))

__device__ __forceinline__ int pk4(float a, float b, float c, float d) {
    int v = __builtin_amdgcn_cvt_pk_fp8_f32(a, b, 0, false);
    v     = __builtin_amdgcn_cvt_pk_fp8_f32(c, d, v, true);
    return v;
}
__device__ __forceinline__ unsigned short f2bf(float f) {
    union { float f; unsigned int u; } v{f};
    unsigned int r = v.u + 0x7FFF + ((v.u >> 16) & 1);   // RNE
    return (unsigned short)(r >> 16);
}
__device__ __forceinline__ float bf2f(unsigned short u) {
    unsigned int v = ((unsigned int)u) << 16;
    return __builtin_bit_cast(float, v);
}

// ---- pre-pass 1: x8 = fp8(x), xbf = bf16(x) ------------------------------
__global__ void cvt_x_kernel(const float* __restrict__ x,
                             unsigned char* __restrict__ x8,
                             unsigned short* __restrict__ xbf, long n) {
    long stride = (long)gridDim.x * blockDim.x * 8;
    for (long j = ((long)blockIdx.x * blockDim.x + threadIdx.x) * 8; j < n; j += stride) {
        float4 v0 = *reinterpret_cast<const float4*>(x + j);
        float4 v1 = *reinterpret_cast<const float4*>(x + j + 4);
        int2 o;
        o.x = pk4(v0.x, v0.y, v0.z, v0.w);
        o.y = pk4(v1.x, v1.y, v1.z, v1.w);
        *reinterpret_cast<int2*>(x8 + j) = o;
        ushort4 b0, b1;
        b0.x = f2bf(v0.x); b0.y = f2bf(v0.y); b0.z = f2bf(v0.z); b0.w = f2bf(v0.w);
        b1.x = f2bf(v1.x); b1.y = f2bf(v1.y); b1.z = f2bf(v1.z); b1.w = f2bf(v1.w);
        *reinterpret_cast<ushort4*>(xbf + j)     = b0;
        *reinterpret_cast<ushort4*>(xbf + j + 4) = b1;
    }
}

// ---- pre-pass 2: W8 = fp8(16*W); M8 = fp8(16*M*pm[col]) ------------------
__global__ void cvt_wm8_kernel(const float* __restrict__ W,
                               const float* __restrict__ Mk,
                               const float* __restrict__ pm,
                               unsigned char* __restrict__ W8,
                               unsigned char* __restrict__ M8, long n) {
    long stride = (long)gridDim.x * blockDim.x * 8;
    for (long j = ((long)blockIdx.x * blockDim.x + threadIdx.x) * 8; j < n; j += stride) {
        float4 w0 = *reinterpret_cast<const float4*>(W + j);
        float4 w1 = *reinterpret_cast<const float4*>(W + j + 4);
        float4 m0 = *reinterpret_cast<const float4*>(Mk + j);
        float4 m1 = *reinterpret_cast<const float4*>(Mk + j + 4);
        const long col = j & (H_DIM - 1);
        float4 p0 = *reinterpret_cast<const float4*>(pm + col);
        float4 p1 = *reinterpret_cast<const float4*>(pm + col + 4);
        int2 ow, om;
        ow.x = pk4(w0.x * 16.f, w0.y * 16.f, w0.z * 16.f, w0.w * 16.f);
        ow.y = pk4(w1.x * 16.f, w1.y * 16.f, w1.z * 16.f, w1.w * 16.f);
        om.x = pk4(m0.x * p0.x * 16.f, m0.y * p0.y * 16.f,
                   m0.z * p0.z * 16.f, m0.w * p0.w * 16.f);
        om.y = pk4(m1.x * p1.x * 16.f, m1.y * p1.y * 16.f,
                   m1.z * p1.z * 16.f, m1.w * p1.w * 16.f);
        *reinterpret_cast<int2*>(W8 + j) = ow;
        *reinterpret_cast<int2*>(M8 + j) = om;
    }
}

// swizzled fp8 frag read: 32 bytes (k-group g) of row `row`.
__device__ __forceinline__ intx8 frag8(const unsigned char* s, int row, int g) {
    const unsigned char* p = s + row * BKB;
    const int c0 = ((2 * g)     ^ (row & 7)) * 16;
    const int c1 = ((2 * g + 1) ^ (row & 7)) * 16;
    intx4 lo = *reinterpret_cast<const intx4*>(p + c0);
    intx4 hi = *reinterpret_cast<const intx4*>(p + c1);
    return (intx8){lo.x, lo.y, lo.z, lo.w, hi.x, hi.y, hi.z, hi.w};
}

#define GLDS(src, dst) __builtin_amdgcn_global_load_lds(GPTR(src), LPTR(dst), 16, 0, 0)

#define STAGE_A(b, kt) do { \
    GLDS(gA0 + (kt),                       &sA[b][(srow      ) * BKB + scol_l]); \
    GLDS(gA0 + (kt) + (size_t)64  * H_DIM, &sA[b][(srow +  64) * BKB + scol_l]); \
    GLDS(gA0 + (kt) + (size_t)128 * H_DIM, &sA[b][(srow + 128) * BKB + scol_l]); \
    GLDS(gA0 + (kt) + (size_t)192 * H_DIM, &sA[b][(srow + 192) * BKB + scol_l]); } while (0)

#define STAGE_W(b, kt) do { \
    GLDS(gW0 + (kt),                       &sW[b][(srow     ) * BKB + scol_l]); \
    GLDS(gW0 + (kt) + (size_t)64  * H_DIM, &sW[b][(srow + 64) * BKB + scol_l]); } while (0)

#define STAGE_M(b, kt) do { \
    GLDS(gM0 + (kt),                       &sM[b][(srow     ) * BKB + scol_l]); \
    GLDS(gM0 + (kt) + (size_t)64  * H_DIM, &sM[b][(srow + 64) * BKB + scol_l]); } while (0)

#define BAR()  __builtin_amdgcn_s_barrier()
#define SBAR() __builtin_amdgcn_sched_barrier(0)
#define LGK0() do { asm volatile("s_waitcnt lgkmcnt(0)" ::: "memory"); SBAR(); } while (0)
#define VMC(n) asm volatile("s_waitcnt vmcnt(" #n ")" ::: "memory")

// scale_a = 127 (2^0) for x; scale_b = 123 (2^-4) undoes the *16 pre-scale.
#define MFMASC(a, b, c) \
    __builtin_amdgcn_mfma_scale_f32_16x16x128_f8f6f4(a, b, c, 0, 0, 0, 127, 0, 123)

#define RD_A(dst, buf) do { \
    _Pragma("unroll") for (int m_ = 0; m_ < 4; ++m_) \
        dst[m_] = frag8(sA[buf], arow + m_ * 16, lg); } while (0)
#define RD_B(dst, sb, buf) do { \
    _Pragma("unroll") for (int n_ = 0; n_ < 4; ++n_) \
        dst[n_] = frag8(sb[buf], brw + n_ * 16, lg); } while (0)

#define MM(acc, av, bv) do { \
    _Pragma("unroll") for (int m_ = 0; m_ < 4; ++m_) \
    _Pragma("unroll") for (int n_ = 0; n_ < 4; ++n_) \
        acc[m_][n_] = MFMASC(av[m_], bv[n_], acc[m_][n_]); } while (0)

// PH_W(t): read A(t),W(t); stage A,W,M(t+1)->nt; acc1 += A*W; drain M(t)
#define PH_W(ct, nt, kst) do { \
    BAR(); \
    RD_A(aF, ct); RD_B(bW, sW, ct); \
    STAGE_A(nt, kst); STAGE_W(nt, kst); STAGE_M(nt, kst); \
    LGK0(); \
    __builtin_amdgcn_s_setprio(1); MM(acc1, aF, bW); __builtin_amdgcn_s_setprio(0); \
    VMC(8); } while (0)

// PH_M(t): read M(t); acc2 += A*M; drain A,W(t+1)
#define PH_M(ct) do { \
    BAR(); \
    RD_B(bM, sM, ct); \
    LGK0(); \
    __builtin_amdgcn_s_setprio(1); MM(acc2, aF, bM); __builtin_amdgcn_s_setprio(0); \
    VMC(2); } while (0)

// ---- fused dual-GEMM + epilogue (persistent, 4 macro-tiles) ---------------
__global__ __launch_bounds__(NTHREADS, 2)
void fused_gemm_kernel(const unsigned char* __restrict__ x8,
                       const unsigned char* __restrict__ W8,
                       const unsigned char* __restrict__ M8,
                       const unsigned short* __restrict__ xbf,
                       const float* __restrict__ bias,
                       const float* __restrict__ pm,
                       float* __restrict__ out) {
    __shared__ __align__(16) unsigned char sA[2][BM * BKB];  // 2 x 32 KB
    __shared__ __align__(16) unsigned char sW[2][BN * BKB];  // 2 x 16 KB
    __shared__ __align__(16) unsigned char sM[2][BN * BKB];  // 2 x 16 KB

    const int t    = threadIdx.x;
    const int id   = blockIdx.x;                 // 256 blocks = 1/CU
    const int bcol = (id & 15) * BN;             // fixed per block (W/M L2-hot)
    const int brow_base = (id >> 4) * (NMACRO * BM);

    const int srow   = t >> 3;
    const int chunk  = t & 7;
    const int scol_l = chunk * 16;
    const int scol_g = (chunk ^ (srow & 7)) * 16;

    const int w    = t >> 6;
    const int lane = t & 63;
    const int wr   = w >> 1;             // 0..3 : 64-row strip
    const int wc   = w & 1;              // 0..1 : 64-col strip
    const int lrow = lane & 15;
    const int lg   = lane >> 4;          // k-group: holds k [32*lg, 32*lg+32)
    const int arow = wr * 64 + lrow;     // A-frag base row (+m*16)
    const int brw  = wc * 64 + lrow;     // B-frag base row (+n*16)

    const unsigned char* gW0 = W8 + (size_t)(bcol + srow) * H_DIM + scol_g;
    const unsigned char* gM0 = M8 + (size_t)(bcol + srow) * H_DIM + scol_g;

    floatx4 acc1[4][4], acc2[4][4];
    intx8 aF[4], bW[4], bM[4];
    unsigned short xpre[4][4][4];        // [n][m][r] epilogue operands

    // initial stage: macro-tile 0, K-tile 0
    {
        const unsigned char* gA0 = x8 + (size_t)(brow_base + srow) * H_DIM + scol_g;
        STAGE_A(0, 0); STAGE_W(0, 0); STAGE_M(0, 0);
    }

    const float c = 0.5f / (float)H_DIM;

#pragma unroll 1
    for (int q = 0; q < NMACRO; ++q) {
        const int brow = brow_base + q * BM;
        const unsigned char* gA0 = x8 + (size_t)(brow + srow) * H_DIM + scol_g;

#pragma unroll
        for (int m = 0; m < 4; ++m)
#pragma unroll
            for (int n = 0; n < 4; ++n) {
                acc1[m][n] = (floatx4){0.f, 0.f, 0.f, 0.f};
                acc2[m][n] = (floatx4){0.f, 0.f, 0.f, 0.f};
            }

        // gate tile-0 stages (FIFO: they are the oldest unretired VMEM ops;
        // q>0 also has <=32 epilogue stores in flight behind them).
        if (q == 0) { VMC(2); } else { VMC(32); }

#pragma unroll 1
        for (int i = 0; i < NKT / 2; ++i) {
            const int ka = ((2 * i + 1) * BKB) & (H_DIM - 1);
            const int kb = ((2 * i + 2) * BKB) & (H_DIM - 1);
            PH_W(0, 1, ka); PH_M(0);
            PH_W(1, 0, kb); PH_M(1);
        }
        // here: <=2 wrap stages outstanding (K-tile 0 of THIS q into buf0)

        // prefetch epilogue xbf operands into registers (32 loads)
#pragma unroll
        for (int n = 0; n < 4; ++n) {
            const int gcol = bcol + wc * 64 + n * 16 + lrow;
#pragma unroll
            for (int m = 0; m < 4; ++m) {
                const int growb = brow + wr * 64 + m * 16 + lg * 4;
#pragma unroll
                for (int r = 0; r < 4; ++r)
                    xpre[n][m][r] = xbf[(size_t)(growb + r) * H_DIM + gcol];
            }
        }

        if (q < NMACRO - 1) {
            // stage next macro-tile's K-tile 0 into buf0 (overwrites wrap
            // stage; same per-thread dest, FIFO order -> new data wins).
            const unsigned char* gA0 = x8 + (size_t)(brow + BM + srow) * H_DIM + scol_g;
            STAGE_A(0, 0); STAGE_W(0, 0); STAGE_M(0, 0);
            VMC(8);   // retires wrap + all 32 xpre; 8 new stages keep flying
        } else {
            VMC(0);   // last macro-tile: just drain everything
        }

        // epilogue: out = xs + sigmoid(S1+b)*xs*S2*c, xs = bf16(x)*pm.
        // stores are fire-and-forget (drained by next q's counted waits).
#pragma unroll
        for (int n = 0; n < 4; ++n) {
            const int gcol = bcol + wc * 64 + n * 16 + lrow;
            const float bj  = bias[gcol];
            const float pmj = pm[gcol];
#pragma unroll
            for (int m = 0; m < 4; ++m) {
                floatx4 a1 = acc1[m][n];
                floatx4 a2 = acc2[m][n];
                const int growb = brow + wr * 64 + m * 16 + lg * 4;
#pragma unroll
                for (int r = 0; r < 4; ++r) {
                    const size_t idx = (size_t)(growb + r) * H_DIM + gcol;
                    const float xs  = bf2f(xpre[n][m][r]) * pmj;
                    const float s1  = a1[r] + bj;
                    const float sig = 1.0f / (1.0f + __expf(-s1));
                    out[idx] = xs + sig * (xs * a2[r] * c);
                }
            }
        }
    }
}

extern "C" void kernel_launch(void* const* d_in, const int* in_sizes, int n_in,
                              void* d_out, int out_size, void* d_ws, size_t ws_size,
                              hipStream_t stream) {
    const float* x   = (const float*)d_in[0];
    const float* W   = (const float*)d_in[1];
    const float* b   = (const float*)d_in[2];
    const float* pm  = (const float*)d_in[3];
    const float* Mk  = (const float*)d_in[4];
    float* out = (float*)d_out;

    const long n_x = (long)M_DIM * H_DIM;      // 33.5M
    const long n_w = (long)H_DIM * H_DIM;      // 4.2M

    // workspace layout (bytes): x8 (33.5MB) | W8 | M8 (4.2MB each) | xbf (67MB)
    unsigned char*  x8  = (unsigned char*)d_ws;
    unsigned char*  W8  = x8 + n_x;
    unsigned char*  M8  = W8 + n_w;
    unsigned short* xbf = (unsigned short*)(M8 + n_w);

    cvt_x_kernel<<<2048, 256, 0, stream>>>(x, x8, xbf, n_x);
    cvt_wm8_kernel<<<1024, 256, 0, stream>>>(W, Mk, pm, W8, M8, n_w);

    fused_gemm_kernel<<<256, NTHREADS, 0, stream>>>(x8, W8, M8, xbf, b, pm, out);
}

// Round 17
// 201.680 us; speedup vs baseline: 1.2953x; 1.2953x over previous
//
#include <hip/hip_runtime.h>

// Problem: B=16384, H=2048
//   bdnf = sigmoid(x @ W^T + b)
//   xs   = x * pm
//   fi   = xs * (xs @ M^T) * (0.5/H)
//   out  = xs + bdnf * fi
// Identity: xs @ M^T = x @ (M * pm[col])^T  -> both GEMMs share A = fp8(x).
//
// FINAL (= R15, best measured: 202us total, GEMM dispatch 178us, absmax
// 0.031 vs 0.094 threshold). Structure: R8's 2-phase counted-vmcnt MX-fp8
// dual GEMM + bf16 epilogue x-read. Ladder: 589 (naive bf16 MFMA) -> 424
// (T2 XOR swizzle) -> 307 (8-phase counted vmcnt) -> 282 (phase-fused reads)
// -> 255 (SGB interleave) -> 190 (MX-fp8 K=128) -> 178 (bf16 epilogue).
// Structural nulls (all ~flat vs R8): merged-barrier single-vmcnt (R9),
// 2-block TLP via smaller blocks (R11), triple-buffer 2-ahead (R12),
// B-bypass-LDS frag-major (R13), XCD swizzle (R14), persistent blocks (R16,
// regressed). Binding constraint: 128KB LDS -> 1 block/CU -> intra-block
// LDS-read/MFMA serialization; MfmaUtil ~34% is this structure's ceiling.
// MX fp8: mfma_scale_f32_16x16x128_f8f6f4, scale_a=127 (2^0),
// scale_b=123 (2^-4, undoes the x16 anti-e4m3-subnormal pre-scale).

#define M_DIM 16384
#define H_DIM 2048
#define BM 256
#define BN 128
#define BKB 128            // K-tile = 128 fp8 elements = 128 B/row
#define NKT (H_DIM / BKB)  // 16 K-tiles
#define NTHREADS 512

typedef __attribute__((ext_vector_type(4))) int   intx4;
typedef __attribute__((ext_vector_type(8))) int   intx8;
typedef __attribute__((ext_vector_type(4))) float floatx4;

#define GPTR(p) ((const __attribute__((address_space(1))) void*)(p))
#define LPTR(p) ((__attribute__((address_space(3))) void*)(p))

__device__ __forceinline__ int pk4(float a, float b, float c, float d) {
    int v = __builtin_amdgcn_cvt_pk_fp8_f32(a, b, 0, false);
    v     = __builtin_amdgcn_cvt_pk_fp8_f32(c, d, v, true);
    return v;
}
__device__ __forceinline__ unsigned short f2bf(float f) {
    union { float f; unsigned int u; } v{f};
    unsigned int r = v.u + 0x7FFF + ((v.u >> 16) & 1);   // RNE
    return (unsigned short)(r >> 16);
}
__device__ __forceinline__ float bf2f(unsigned short u) {
    unsigned int v = ((unsigned int)u) << 16;
    return __builtin_bit_cast(float, v);
}

// ---- pre-pass 1: x8 = fp8(x), xbf = bf16(x) ------------------------------
__global__ void cvt_x_kernel(const float* __restrict__ x,
                             unsigned char* __restrict__ x8,
                             unsigned short* __restrict__ xbf, long n) {
    long stride = (long)gridDim.x * blockDim.x * 8;
    for (long j = ((long)blockIdx.x * blockDim.x + threadIdx.x) * 8; j < n; j += stride) {
        float4 v0 = *reinterpret_cast<const float4*>(x + j);
        float4 v1 = *reinterpret_cast<const float4*>(x + j + 4);
        int2 o;
        o.x = pk4(v0.x, v0.y, v0.z, v0.w);
        o.y = pk4(v1.x, v1.y, v1.z, v1.w);
        *reinterpret_cast<int2*>(x8 + j) = o;
        ushort4 b0, b1;
        b0.x = f2bf(v0.x); b0.y = f2bf(v0.y); b0.z = f2bf(v0.z); b0.w = f2bf(v0.w);
        b1.x = f2bf(v1.x); b1.y = f2bf(v1.y); b1.z = f2bf(v1.z); b1.w = f2bf(v1.w);
        *reinterpret_cast<ushort4*>(xbf + j)     = b0;
        *reinterpret_cast<ushort4*>(xbf + j + 4) = b1;
    }
}

// ---- pre-pass 2: W8 = fp8(16*W); M8 = fp8(16*M*pm[col]) ------------------
__global__ void cvt_wm8_kernel(const float* __restrict__ W,
                               const float* __restrict__ Mk,
                               const float* __restrict__ pm,
                               unsigned char* __restrict__ W8,
                               unsigned char* __restrict__ M8, long n) {
    long stride = (long)gridDim.x * blockDim.x * 8;
    for (long j = ((long)blockIdx.x * blockDim.x + threadIdx.x) * 8; j < n; j += stride) {
        float4 w0 = *reinterpret_cast<const float4*>(W + j);
        float4 w1 = *reinterpret_cast<const float4*>(W + j + 4);
        float4 m0 = *reinterpret_cast<const float4*>(Mk + j);
        float4 m1 = *reinterpret_cast<const float4*>(Mk + j + 4);
        const long col = j & (H_DIM - 1);
        float4 p0 = *reinterpret_cast<const float4*>(pm + col);
        float4 p1 = *reinterpret_cast<const float4*>(pm + col + 4);
        int2 ow, om;
        ow.x = pk4(w0.x * 16.f, w0.y * 16.f, w0.z * 16.f, w0.w * 16.f);
        ow.y = pk4(w1.x * 16.f, w1.y * 16.f, w1.z * 16.f, w1.w * 16.f);
        om.x = pk4(m0.x * p0.x * 16.f, m0.y * p0.y * 16.f,
                   m0.z * p0.z * 16.f, m0.w * p0.w * 16.f);
        om.y = pk4(m1.x * p1.x * 16.f, m1.y * p1.y * 16.f,
                   m1.z * p1.z * 16.f, m1.w * p1.w * 16.f);
        *reinterpret_cast<int2*>(W8 + j) = ow;
        *reinterpret_cast<int2*>(M8 + j) = om;
    }
}

// swizzled fp8 frag read: 32 bytes (k-group g) of row `row`.
// LDS chunk slot c holds global chunk c^(row&7).
__device__ __forceinline__ intx8 frag8(const unsigned char* s, int row, int g) {
    const unsigned char* p = s + row * BKB;
    const int c0 = ((2 * g)     ^ (row & 7)) * 16;
    const int c1 = ((2 * g + 1) ^ (row & 7)) * 16;
    intx4 lo = *reinterpret_cast<const intx4*>(p + c0);
    intx4 hi = *reinterpret_cast<const intx4*>(p + c1);
    return (intx8){lo.x, lo.y, lo.z, lo.w, hi.x, hi.y, hi.z, hi.w};
}

#define GLDS(src, dst) __builtin_amdgcn_global_load_lds(GPTR(src), LPTR(dst), 16, 0, 0)

#define STAGE_A(b, kt) do { \
    GLDS(gA0 + (kt),                       &sA[b][(srow      ) * BKB + scol_l]); \
    GLDS(gA0 + (kt) + (size_t)64  * H_DIM, &sA[b][(srow +  64) * BKB + scol_l]); \
    GLDS(gA0 + (kt) + (size_t)128 * H_DIM, &sA[b][(srow + 128) * BKB + scol_l]); \
    GLDS(gA0 + (kt) + (size_t)192 * H_DIM, &sA[b][(srow + 192) * BKB + scol_l]); } while (0)

#define STAGE_W(b, kt) do { \
    GLDS(gW0 + (kt),                       &sW[b][(srow     ) * BKB + scol_l]); \
    GLDS(gW0 + (kt) + (size_t)64  * H_DIM, &sW[b][(srow + 64) * BKB + scol_l]); } while (0)

#define STAGE_M(b, kt) do { \
    GLDS(gM0 + (kt),                       &sM[b][(srow     ) * BKB + scol_l]); \
    GLDS(gM0 + (kt) + (size_t)64  * H_DIM, &sM[b][(srow + 64) * BKB + scol_l]); } while (0)

#define BAR()  __builtin_amdgcn_s_barrier()
#define SBAR() __builtin_amdgcn_sched_barrier(0)
#define LGK0() do { asm volatile("s_waitcnt lgkmcnt(0)" ::: "memory"); SBAR(); } while (0)
#define VMC(n) asm volatile("s_waitcnt vmcnt(" #n ")" ::: "memory")

// scale_a = 127 (2^0) for x; scale_b = 123 (2^-4) undoes the *16 pre-scale.
#define MFMASC(a, b, c) \
    __builtin_amdgcn_mfma_scale_f32_16x16x128_f8f6f4(a, b, c, 0, 0, 0, 127, 0, 123)

#define RD_A(dst, buf) do { \
    _Pragma("unroll") for (int m_ = 0; m_ < 4; ++m_) \
        dst[m_] = frag8(sA[buf], arow + m_ * 16, lg); } while (0)
#define RD_B(dst, sb, buf) do { \
    _Pragma("unroll") for (int n_ = 0; n_ < 4; ++n_) \
        dst[n_] = frag8(sb[buf], brw + n_ * 16, lg); } while (0)

#define MM(acc, av, bv) do { \
    _Pragma("unroll") for (int m_ = 0; m_ < 4; ++m_) \
    _Pragma("unroll") for (int n_ = 0; n_ < 4; ++n_) \
        acc[m_][n_] = MFMASC(av[m_], bv[n_], acc[m_][n_]); } while (0)

// PH_W(t): read A(t),W(t); stage A,W,M(t+1)->nt; acc1 += A*W; drain M(t)
#define PH_W(ct, nt, kst) do { \
    BAR(); \
    RD_A(aF, ct); RD_B(bW, sW, ct); \
    STAGE_A(nt, kst); STAGE_W(nt, kst); STAGE_M(nt, kst); \
    LGK0(); \
    __builtin_amdgcn_s_setprio(1); MM(acc1, aF, bW); __builtin_amdgcn_s_setprio(0); \
    VMC(8); } while (0)

// PH_M(t): read M(t); acc2 += A*M; drain A,W(t+1)
#define PH_M(ct) do { \
    BAR(); \
    RD_B(bM, sM, ct); \
    LGK0(); \
    __builtin_amdgcn_s_setprio(1); MM(acc2, aF, bM); __builtin_amdgcn_s_setprio(0); \
    VMC(2); } while (0)

// ---- fused dual-GEMM + epilogue ------------------------------------------
__global__ __launch_bounds__(NTHREADS, 2)
void fused_gemm_kernel(const unsigned char* __restrict__ x8,
                       const unsigned char* __restrict__ W8,
                       const unsigned char* __restrict__ M8,
                       const unsigned short* __restrict__ xbf,
                       const float* __restrict__ bias,
                       const float* __restrict__ pm,
                       float* __restrict__ out) {
    __shared__ __align__(16) unsigned char sA[2][BM * BKB];  // 2 x 32 KB
    __shared__ __align__(16) unsigned char sW[2][BN * BKB];  // 2 x 16 KB
    __shared__ __align__(16) unsigned char sM[2][BN * BKB];  // 2 x 16 KB

    const int t    = threadIdx.x;
    const int brow = blockIdx.y * BM;
    const int bcol = blockIdx.x * BN;

    // staging: thread t covers row srow (+64/128/192), 16B chunk (t&7);
    // LDS dest linear, global source chunk pre-swizzled with srow&7.
    const int srow   = t >> 3;
    const int chunk  = t & 7;
    const int scol_l = chunk * 16;
    const int scol_g = (chunk ^ (srow & 7)) * 16;

    const int w    = t >> 6;
    const int lane = t & 63;
    const int wr   = w >> 1;             // 0..3 : 64-row strip
    const int wc   = w & 1;              // 0..1 : 64-col strip
    const int lrow = lane & 15;
    const int lg   = lane >> 4;          // k-group: holds k [32*lg, 32*lg+32)
    const int arow = wr * 64 + lrow;     // A-frag base row (+m*16)
    const int brw  = wc * 64 + lrow;     // B-frag base row (+n*16)

    floatx4 acc1[4][4], acc2[4][4];
#pragma unroll
    for (int m = 0; m < 4; ++m)
#pragma unroll
        for (int n = 0; n < 4; ++n) {
            acc1[m][n] = (floatx4){0.f, 0.f, 0.f, 0.f};
            acc2[m][n] = (floatx4){0.f, 0.f, 0.f, 0.f};
        }

    const unsigned char* gA0 = x8 + (size_t)(brow + srow) * H_DIM + scol_g;
    const unsigned char* gW0 = W8 + (size_t)(bcol + srow) * H_DIM + scol_g;
    const unsigned char* gM0 = M8 + (size_t)(bcol + srow) * H_DIM + scol_g;

    intx8 aF[4], bW[4], bM[4];

    // prologue: stage tile 0 (A:4,W:2,M:2); drain A0,W0 (M0 drains at
    // PH_W(0)'s vmcnt(8)); first PH_W's BAR confirms all waves' stages.
    STAGE_A(0, 0); STAGE_W(0, 0); STAGE_M(0, 0);
    VMC(2);

#pragma unroll 1
    for (int i = 0; i < NKT / 2; ++i) {
        const int ka = ((2 * i + 1) * BKB) & (H_DIM - 1);  // stage for odd tile
        const int kb = ((2 * i + 2) * BKB) & (H_DIM - 1);  // stage for next even
        PH_W(0, 1, ka); PH_M(0);
        PH_W(1, 0, kb); PH_M(1);
    }

    // epilogue: out = xs + sigmoid(S1+b)*xs*S2*(0.5/H), xs = bf16(x)*pm
    const float c = 0.5f / (float)H_DIM;
#pragma unroll
    for (int n = 0; n < 4; ++n) {
        const int gcol = bcol + wc * 64 + n * 16 + lrow;
        const float bj  = bias[gcol];
        const float pmj = pm[gcol];
#pragma unroll
        for (int m = 0; m < 4; ++m) {
            floatx4 a1 = acc1[m][n];
            floatx4 a2 = acc2[m][n];
            const int growb = brow + wr * 64 + m * 16 + lg * 4;
#pragma unroll
            for (int r = 0; r < 4; ++r) {
                const size_t idx = (size_t)(growb + r) * H_DIM + gcol;
                const float xs  = bf2f(xbf[idx]) * pmj;
                const float s1  = a1[r] + bj;
                const float sig = 1.0f / (1.0f + __expf(-s1));
                out[idx] = xs + sig * (xs * a2[r] * c);
            }
        }
    }
}

extern "C" void kernel_launch(void* const* d_in, const int* in_sizes, int n_in,
                              void* d_out, int out_size, void* d_ws, size_t ws_size,
                              hipStream_t stream) {
    const float* x   = (const float*)d_in[0];
    const float* W   = (const float*)d_in[1];
    const float* b   = (const float*)d_in[2];
    const float* pm  = (const float*)d_in[3];
    const float* Mk  = (const float*)d_in[4];
    float* out = (float*)d_out;

    const long n_x = (long)M_DIM * H_DIM;      // 33.5M
    const long n_w = (long)H_DIM * H_DIM;      // 4.2M

    // workspace layout (bytes): x8 (33.5MB) | W8 | M8 (4.2MB each) | xbf (67MB)
    unsigned char*  x8  = (unsigned char*)d_ws;
    unsigned char*  W8  = x8 + n_x;
    unsigned char*  M8  = W8 + n_w;
    unsigned short* xbf = (unsigned short*)(M8 + n_w);

    cvt_x_kernel<<<2048, 256, 0, stream>>>(x, x8, xbf, n_x);
    cvt_wm8_kernel<<<1024, 256, 0, stream>>>(W, Mk, pm, W8, M8, n_w);

    dim3 grid(H_DIM / BN, M_DIM / BM);   // (16, 64)
    fused_gemm_kernel<<<grid, NTHREADS, 0, stream>>>(x8, W8, M8, xbf, b, pm, out);
}